// Round 3
// baseline (97.039 us; speedup 1.0000x reference)
//
#include <hip/hip_runtime.h>
#include <hip/hip_bf16.h>

#define BATCH 8
#define SEQ   4096
#define NST   512     // state dim == GEMM K
#define DM    512     // d_model  == GEMM N
#define NCHUNK 64
#define TCH    64     // SEQ / NCHUNK

typedef __attribute__((ext_vector_type(4))) float f32x4;
typedef __attribute__((ext_vector_type(2))) float f32x2;
typedef __attribute__((ext_vector_type(8))) short short8v;   // 8 bf16
typedef __attribute__((ext_vector_type(4))) short short4v;

__device__ __forceinline__ short f2bf(float f) {
  union { float f; unsigned u; } v; v.f = f;
  unsigned r = v.u + 0x7FFFu + ((v.u >> 16) & 1u);   // RNE truncate to bf16
  return (short)(r >> 16);
}

// K1a: per-chunk local scan sums S[c][b][n], f32x2 per thread, unroll 8
__global__ void k_scan_sums(const float* __restrict__ u, const float* __restrict__ Lam,
                            const float* __restrict__ Bv, const float* __restrict__ log_dt,
                            float* __restrict__ S) {
  int gid = blockIdx.x * 256 + threadIdx.x;      // [0, NCHUNK*BATCH*256)
  int n2 = (gid & 255) * 2;
  int bc = gid >> 8;
  int b  = bc & (BATCH - 1);
  int c  = bc >> 3;
  float dt = expf(log_dt[0]);
  f32x2 lam = *(const f32x2*)(Lam + n2);
  f32x2 bv  = *(const f32x2*)(Bv + n2);
  float a0 = expf(-dt * expf(lam[0])), a1 = expf(-dt * expf(lam[1]));
  float g0 = dt * bv[0],               g1 = dt * bv[1];
  const float* up = u + ((size_t)b * SEQ + (size_t)c * TCH) * NST + n2;
  float s0 = 0.f, s1 = 0.f;
  #pragma unroll 8
  for (int t = 0; t < TCH; ++t) {
    f32x2 v = *(const f32x2*)(up + (size_t)t * NST);
    s0 = fmaf(a0, s0, g0 * v[0]);
    s1 = fmaf(a1, s1, g1 * v[1]);
  }
  *(f32x2*)(S + (c * BATCH + b) * NST + n2) = (f32x2){s0, s1};
}

// K2: sequential chunk-state propagation: Xc[c] = incoming state of chunk c
__global__ void k_propagate(const float* __restrict__ Lam, const float* __restrict__ log_dt,
                            const float* __restrict__ S, float* __restrict__ Xc) {
  int gid = blockIdx.x * 256 + threadIdx.x;      // [0, BATCH*NST)
  int n = gid & (NST - 1);
  int b = gid >> 9;
  float dt = expf(log_dt[0]);
  float a  = expf(-dt * expf(Lam[n]));
  float aT = a;
  #pragma unroll
  for (int i = 0; i < 6; ++i) aT *= aT;          // a^64 = a^TCH
  float x = 0.f;
  for (int c = 0; c < NCHUNK; ++c) {
    Xc[(c * BATCH + b) * NST + n] = x;
    x = fmaf(aT, x, S[(c * BATCH + b) * NST + n]);
  }
}

// K2c: Qt[d][n] = bf16(Q[n][d]) via LDS tile transpose (coalesced both sides)
__global__ void k_transQ(const float* __restrict__ Q, short* __restrict__ Qt) {
  __shared__ short tile[64][68];
  int bn = (blockIdx.x & 7) * 64;                // n tile base
  int bd = (blockIdx.x >> 3) * 64;               // d tile base
  int tc = threadIdx.x & 15;                     // 16 col-quads
  int tr = threadIdx.x >> 4;                     // 16 rows per pass
  #pragma unroll
  for (int i = 0; i < 4; ++i) {
    int r = tr + i * 16;                         // n-local
    f32x4 v = *(const f32x4*)(Q + (size_t)(bn + r) * DM + bd + tc * 4);
    short4v h;
    h[0] = f2bf(v[0]); h[1] = f2bf(v[1]); h[2] = f2bf(v[2]); h[3] = f2bf(v[3]);
    *(short4v*)&tile[r][tc * 4] = h;
  }
  __syncthreads();
  #pragma unroll
  for (int i = 0; i < 4; ++i) {
    int r = tr + i * 16;                         // d-local
    short4v h;
    #pragma unroll
    for (int j = 0; j < 4; ++j) h[j] = tile[tc * 4 + j][r];
    *(short4v*)(Qt + (size_t)(bd + r) * NST + bn + tc * 4) = h;
  }
}

// K3 fused: seeded local scan -> x tile in LDS (bf16) -> barrier-free GEMM -> coalesced y
// TCH=64 -> LDS 66.5 KB -> 2 blocks/CU (16 waves/CU) so co-resident blocks overlap phases.
__global__ __launch_bounds__(512, 4) void k_fused(
    const float* __restrict__ u, const float* __restrict__ Lam,
    const float* __restrict__ Bv, const float* __restrict__ log_dt,
    const float* __restrict__ Xc, const short* __restrict__ Qt,
    float* __restrict__ y) {
  __shared__ __align__(16) short X[TCH][NST + 8];   // 64 x 520 shorts = 66.5 KB
  const int tid = threadIdx.x;
  const int b = blockIdx.x & (BATCH - 1);
  const int c = blockIdx.x >> 3;

  // ---- phase 1: seeded scan, x -> LDS bf16 ----
  {
    const int n = tid;
    float dt = expf(log_dt[0]);
    float a  = expf(-dt * expf(Lam[n]));
    float g  = dt * Bv[n];
    float x  = Xc[(c * BATCH + b) * NST + n];
    const float* up = u + ((size_t)b * SEQ + (size_t)c * TCH) * NST + n;
    #pragma unroll 16
    for (int t = 0; t < TCH; ++t) {
      x = fmaf(a, x, g * up[(size_t)t * NST]);
      X[t][n] = f2bf(x);
    }
  }
  __syncthreads();

  // ---- phase 2: GEMM 64x512x512, A from LDS, B from L2-resident Qt ----
  const int lane = tid & 63;
  const int wid  = tid >> 6;
  const int wr   = wid >> 2;                     // 0..1 (row half: 32 rows)
  const int wc   = wid & 3;                      // 0..3 (col quarter: 128 cols)
  const int l15  = lane & 15;
  const int lhi  = lane >> 4;
  const int ka   = lhi * 8;

  f32x4 acc[2][8];
  #pragma unroll
  for (int mi = 0; mi < 2; ++mi)
    #pragma unroll
    for (int nf = 0; nf < 8; ++nf) acc[mi][nf] = (f32x4){0.f, 0.f, 0.f, 0.f};

  for (int k0 = 0; k0 < NST; k0 += 32) {
    short8v afrag[2];
    #pragma unroll
    for (int mi = 0; mi < 2; ++mi)
      afrag[mi] = *(const short8v*)&X[wr * 32 + mi * 16 + l15][k0 + ka];
    short8v bfrag[8];
    #pragma unroll
    for (int nf = 0; nf < 8; ++nf)
      bfrag[nf] = *(const short8v*)(Qt + (size_t)(wc * 128 + nf * 16 + l15) * NST + k0 + ka);
    #pragma unroll
    for (int mi = 0; mi < 2; ++mi)
      #pragma unroll
      for (int nf = 0; nf < 8; ++nf)
        acc[mi][nf] = __builtin_amdgcn_mfma_f32_16x16x32_bf16(afrag[mi], bfrag[nf], acc[mi][nf], 0, 0, 0);
  }
  __syncthreads();                               // done reading X; reuse LDS for Y staging

  // ---- phase 3: epilogue, LDS-staged coalesced nontemporal stores (2 groups of 32 rows) ----
  float* Yb = (float*)&X[0][0];                  // 32*512 f32 = 64 KB (fits in X)
  #pragma unroll
  for (int g = 0; g < 2; ++g) {
    if (wr == g) {
      #pragma unroll
      for (int mi = 0; mi < 2; ++mi) {
        #pragma unroll
        for (int nf = 0; nf < 8; ++nf) {
          const int r0 = mi * 16 + lhi * 4;
          const int cc = wc * 128 + nf * 16 + l15;
          #pragma unroll
          for (int i = 0; i < 4; ++i)
            Yb[(r0 + i) * DM + cc] = acc[mi][nf][i];
        }
      }
    }
    __syncthreads();
    const size_t rowbase = (size_t)b * SEQ + (size_t)c * TCH + g * 32;
    #pragma unroll
    for (int j = 0; j < 8; ++j) {
      const int q  = tid + j * 512;              // f32x4 index in [0, 4096)
      const int fi = q * 4;
      const int r  = fi >> 9;
      const int col = fi & (DM - 1);
      __builtin_nontemporal_store(*(const f32x4*)(Yb + fi),
                                  (f32x4*)(y + (rowbase + r) * DM + col));
    }
    __syncthreads();
  }
}

extern "C" void kernel_launch(void* const* d_in, const int* in_sizes, int n_in,
                              void* d_out, int out_size, void* d_ws, size_t ws_size,
                              hipStream_t stream) {
  const float* u      = (const float*)d_in[0];
  const float* Lam    = (const float*)d_in[1];
  const float* Bv     = (const float*)d_in[2];
  const float* Q      = (const float*)d_in[3];
  const float* log_dt = (const float*)d_in[4];
  float* out = (float*)d_out;

  float* S  = (float*)d_ws;                                  // 1 MB
  float* Xc = S + NCHUNK * BATCH * NST;                      // 1 MB
  short* Qt = (short*)(Xc + NCHUNK * BATCH * NST);           // 512 KB bf16

  hipLaunchKernelGGL(k_scan_sums, dim3(NCHUNK * BATCH), dim3(256), 0, stream,
                     u, Lam, Bv, log_dt, S);
  hipLaunchKernelGGL(k_propagate, dim3(BATCH * NST / 256), dim3(256), 0, stream,
                     Lam, log_dt, S, Xc);
  hipLaunchKernelGGL(k_transQ, dim3(64), dim3(256), 0, stream, Q, Qt);
  hipLaunchKernelGGL(k_fused, dim3(NCHUNK * BATCH), dim3(512), 0, stream,
                     u, Lam, Bv, log_dt, Xc, Qt, out);
}

// Round 4
// 65.546 us; speedup vs baseline: 1.4805x; 1.4805x over previous
//
#include <hip/hip_runtime.h>
#include <hip/hip_bf16.h>

#define BATCH 8
#define SEQ   4096
#define NST   512     // state dim == GEMM K
#define DM    512     // d_model  == GEMM N
#define NCHUNK 32
#define TCH    128    // SEQ / NCHUNK
#define ST     64     // subtile rows (pipeline stage)
#define LDP    (NST + 8)   // LDS row pitch in shorts (2-way bank alias only)

typedef __attribute__((ext_vector_type(4))) float f32x4;
typedef __attribute__((ext_vector_type(2))) float f32x2;
typedef __attribute__((ext_vector_type(8))) short short8v;   // 8 bf16
typedef __attribute__((ext_vector_type(4))) short short4v;

__device__ __forceinline__ short f2bf(float f) {
  union { float f; unsigned u; } v; v.f = f;
  unsigned r = v.u + 0x7FFFu + ((v.u >> 16) & 1u);   // RNE truncate to bf16
  return (short)(r >> 16);
}

// K1a: per-chunk local scan sums S[c][b][n], f32x2 per thread, unroll 8
__global__ void k_scan_sums(const float* __restrict__ u, const float* __restrict__ Lam,
                            const float* __restrict__ Bv, const float* __restrict__ log_dt,
                            float* __restrict__ S) {
  int gid = blockIdx.x * 256 + threadIdx.x;      // [0, NCHUNK*BATCH*256)
  int n2 = (gid & 255) * 2;
  int bc = gid >> 8;
  int b  = bc & (BATCH - 1);
  int c  = bc >> 3;
  float dt = expf(log_dt[0]);
  f32x2 lam = *(const f32x2*)(Lam + n2);
  f32x2 bv  = *(const f32x2*)(Bv + n2);
  float a0 = expf(-dt * expf(lam[0])), a1 = expf(-dt * expf(lam[1]));
  float g0 = dt * bv[0],               g1 = dt * bv[1];
  const float* up = u + ((size_t)b * SEQ + (size_t)c * TCH) * NST + n2;
  float s0 = 0.f, s1 = 0.f;
  #pragma unroll 8
  for (int t = 0; t < TCH; ++t) {
    f32x2 v = *(const f32x2*)(up + (size_t)t * NST);
    s0 = fmaf(a0, s0, g0 * v[0]);
    s1 = fmaf(a1, s1, g1 * v[1]);
  }
  *(f32x2*)(S + (c * BATCH + b) * NST + n2) = (f32x2){s0, s1};
}

// K2: sequential chunk-state propagation: Xc[c] = incoming state of chunk c
__global__ void k_propagate(const float* __restrict__ Lam, const float* __restrict__ log_dt,
                            const float* __restrict__ S, float* __restrict__ Xc) {
  int gid = blockIdx.x * 256 + threadIdx.x;      // [0, BATCH*NST)
  int n = gid & (NST - 1);
  int b = gid >> 9;
  float dt = expf(log_dt[0]);
  float a  = expf(-dt * expf(Lam[n]));
  float aT = a;
  #pragma unroll
  for (int i = 0; i < 7; ++i) aT *= aT;          // a^128 = a^TCH
  float x = 0.f;
  for (int c = 0; c < NCHUNK; ++c) {
    Xc[(c * BATCH + b) * NST + n] = x;
    x = fmaf(aT, x, S[(c * BATCH + b) * NST + n]);
  }
}

// K2c: Qt[d][n] = bf16(Q[n][d]) via LDS tile transpose (coalesced both sides)
__global__ void k_transQ(const float* __restrict__ Q, short* __restrict__ Qt) {
  __shared__ short tile[64][68];
  int bn = (blockIdx.x & 7) * 64;                // n tile base
  int bd = (blockIdx.x >> 3) * 64;               // d tile base
  int tc = threadIdx.x & 15;                     // 16 col-quads
  int tr = threadIdx.x >> 4;                     // 16 rows per pass
  #pragma unroll
  for (int i = 0; i < 4; ++i) {
    int r = tr + i * 16;                         // n-local
    f32x4 v = *(const f32x4*)(Q + (size_t)(bn + r) * DM + bd + tc * 4);
    short4v h;
    h[0] = f2bf(v[0]); h[1] = f2bf(v[1]); h[2] = f2bf(v[2]); h[3] = f2bf(v[3]);
    *(short4v*)&tile[r][tc * 4] = h;
  }
  __syncthreads();
  #pragma unroll
  for (int i = 0; i < 4; ++i) {
    int r = tr + i * 16;                         // d-local
    short4v h;
    #pragma unroll
    for (int j = 0; j < 4; ++j) h[j] = tile[tc * 4 + j][r];
    *(short4v*)(Qt + (size_t)(bd + r) * NST + bn + tc * 4) = h;
  }
}

// K3 fused, software-pipelined: scan(s0) -> [GEMM(s0) || u-loads(s1)] -> scan(s1) -> GEMM(s1)
// 1 block/CU, 512 threads (8 waves, 1x8 col split), double-buffered 64-row X tiles.
__global__ __launch_bounds__(512) void k_fused(
    const float* __restrict__ u, const float* __restrict__ Lam,
    const float* __restrict__ Bv, const float* __restrict__ log_dt,
    const float* __restrict__ Xc, const short* __restrict__ Qt,
    float* __restrict__ y) {
  __shared__ __align__(16) short X[2][ST][LDP];   // 2 x 64 x 520 shorts = 133120 B
  const int tid = threadIdx.x;
  const int b = blockIdx.x & (BATCH - 1);
  const int c = blockIdx.x >> 3;

  // scan coefficients (thread tid owns state column n = tid)
  const float dt = expf(log_dt[0]);
  const float a  = expf(-dt * expf(Lam[tid]));
  const float g  = dt * Bv[tid];
  float x = Xc[(c * BATCH + b) * NST + tid];
  const float* up = u + ((size_t)b * SEQ + (size_t)c * TCH) * NST + tid;

  // ---- prologue: scan subtile 0 (rows 0..63) into X[0] ----
  {
    float ur[ST];
    #pragma unroll
    for (int t = 0; t < ST; ++t) ur[t] = up[(size_t)t * NST];
    #pragma unroll
    for (int t = 0; t < ST; ++t) {
      x = fmaf(a, x, g * ur[t]);
      X[0][t][tid] = f2bf(x);
    }
  }
  __syncthreads();

  // GEMM thread mapping: wave wc owns 64 cols [wc*64, wc*64+64), all 64 rows
  const int lane = tid & 63;
  const int wc   = tid >> 6;                     // 0..7
  const int l15  = lane & 15;
  const int lhi  = lane >> 4;
  const int ka   = lhi * 8;                      // k offset within BK=32
  const short* qbase = Qt + (size_t)(wc * 64 + l15) * NST + ka;
  float* yb = y + ((size_t)b * SEQ + (size_t)c * TCH) * DM;

  float ur2[ST];                                 // subtile-1 u values, loaded during GEMM(0)
  f32x4 acc[4][4];
  #pragma unroll
  for (int mi = 0; mi < 4; ++mi)
    #pragma unroll
    for (int nf = 0; nf < 4; ++nf) acc[mi][nf] = (f32x4){0.f, 0.f, 0.f, 0.f};

  // ---- GEMM subtile 0, with subtile-1 u-loads embedded (4 per K-step) ----
  #pragma unroll
  for (int kk = 0; kk < 16; ++kk) {
    const int k0 = kk * 32;
    #pragma unroll
    for (int j = 0; j < 4; ++j)
      ur2[kk * 4 + j] = up[(size_t)(ST + kk * 4 + j) * NST];
    short8v afrag[4];
    #pragma unroll
    for (int mi = 0; mi < 4; ++mi)
      afrag[mi] = *(const short8v*)&X[0][mi * 16 + l15][k0 + ka];
    short8v bfrag[4];
    #pragma unroll
    for (int nf = 0; nf < 4; ++nf)
      bfrag[nf] = *(const short8v*)(qbase + (size_t)nf * 16 * NST + k0);
    #pragma unroll
    for (int mi = 0; mi < 4; ++mi)
      #pragma unroll
      for (int nf = 0; nf < 4; ++nf)
        acc[mi][nf] = __builtin_amdgcn_mfma_f32_16x16x32_bf16(afrag[mi], bfrag[nf], acc[mi][nf], 0, 0, 0);
  }

  // ---- y stores subtile 0 (each instr: 4 rows x 16 consecutive cols = full 64B lines) ----
  #pragma unroll
  for (int mi = 0; mi < 4; ++mi)
    #pragma unroll
    for (int nf = 0; nf < 4; ++nf) {
      const int rr = mi * 16 + lhi * 4;
      const int cc = wc * 64 + nf * 16 + l15;
      #pragma unroll
      for (int i = 0; i < 4; ++i)
        yb[(size_t)(rr + i) * DM + cc] = acc[mi][nf][i];
    }

  // ---- scan subtile 1 (VALU chain on already-loaded ur2) into X[1] ----
  #pragma unroll
  for (int t = 0; t < ST; ++t) {
    x = fmaf(a, x, g * ur2[t]);
    X[1][t][tid] = f2bf(x);
  }
  __syncthreads();

  // ---- GEMM subtile 1 ----
  #pragma unroll
  for (int mi = 0; mi < 4; ++mi)
    #pragma unroll
    for (int nf = 0; nf < 4; ++nf) acc[mi][nf] = (f32x4){0.f, 0.f, 0.f, 0.f};

  #pragma unroll
  for (int kk = 0; kk < 16; ++kk) {
    const int k0 = kk * 32;
    short8v afrag[4];
    #pragma unroll
    for (int mi = 0; mi < 4; ++mi)
      afrag[mi] = *(const short8v*)&X[1][mi * 16 + l15][k0 + ka];
    short8v bfrag[4];
    #pragma unroll
    for (int nf = 0; nf < 4; ++nf)
      bfrag[nf] = *(const short8v*)(qbase + (size_t)nf * 16 * NST + k0);
    #pragma unroll
    for (int mi = 0; mi < 4; ++mi)
      #pragma unroll
      for (int nf = 0; nf < 4; ++nf)
        acc[mi][nf] = __builtin_amdgcn_mfma_f32_16x16x32_bf16(afrag[mi], bfrag[nf], acc[mi][nf], 0, 0, 0);
  }

  // ---- y stores subtile 1 (rows +64) ----
  #pragma unroll
  for (int mi = 0; mi < 4; ++mi)
    #pragma unroll
    for (int nf = 0; nf < 4; ++nf) {
      const int rr = ST + mi * 16 + lhi * 4;
      const int cc = wc * 64 + nf * 16 + l15;
      #pragma unroll
      for (int i = 0; i < 4; ++i)
        yb[(size_t)(rr + i) * DM + cc] = acc[mi][nf][i];
    }
}

extern "C" void kernel_launch(void* const* d_in, const int* in_sizes, int n_in,
                              void* d_out, int out_size, void* d_ws, size_t ws_size,
                              hipStream_t stream) {
  const float* u      = (const float*)d_in[0];
  const float* Lam    = (const float*)d_in[1];
  const float* Bv     = (const float*)d_in[2];
  const float* Q      = (const float*)d_in[3];
  const float* log_dt = (const float*)d_in[4];
  float* out = (float*)d_out;

  float* S  = (float*)d_ws;                                  // 512 KB
  float* Xc = S + NCHUNK * BATCH * NST;                      // 512 KB
  short* Qt = (short*)(Xc + NCHUNK * BATCH * NST);           // 512 KB bf16

  hipLaunchKernelGGL(k_scan_sums, dim3(NCHUNK * BATCH), dim3(256), 0, stream,
                     u, Lam, Bv, log_dt, S);
  hipLaunchKernelGGL(k_propagate, dim3(BATCH * NST / 256), dim3(256), 0, stream,
                     Lam, log_dt, S, Xc);
  hipLaunchKernelGGL(k_transQ, dim3(64), dim3(256), 0, stream, Q, Qt);
  hipLaunchKernelGGL(k_fused, dim3(NCHUNK * BATCH), dim3(512), 0, stream,
                     u, Lam, Bv, log_dt, Xc, Qt, out);
}